// Round 2
// baseline (12831.749 us; speedup 1.0000x reference)
//
#include <hip/hip_runtime.h>

typedef unsigned int u32;
typedef short short4v __attribute__((ext_vector_type(4)));
typedef short short8v __attribute__((ext_vector_type(8)));
typedef float f32x4 __attribute__((ext_vector_type(4)));

#define Tn 1024
#define Bn 32
#define Hn 1024
#define NWG 32

__device__ __forceinline__ float bf2f(short s) {
  u32 u = ((u32)(unsigned short)s) << 16;
  return __builtin_bit_cast(float, u);
}
__device__ __forceinline__ short f2bf(float f) {
  u32 u = __builtin_bit_cast(u32, f);
  u32 r = (u + 0x7fffu + ((u >> 16) & 1u)) >> 16;
  return (short)(unsigned short)r;
}

__device__ __forceinline__ void gl_lds16(const void* g, void* l) {
  __builtin_amdgcn_global_load_lds(
      (const __attribute__((address_space(1))) u32*)g,
      (__attribute__((address_space(3))) u32*)l, 16, 0, 0);
}

// ---------------- fp32 -> bf16 conversion (vectorized) ----------------
__global__ __launch_bounds__(256) void cvt_bf16(const float* __restrict__ in,
                                                short* __restrict__ out, int n8) {
  int stride = gridDim.x * 256;
  for (int i = blockIdx.x * 256 + threadIdx.x; i < n8; i += stride) {
    const f32x4* p = (const f32x4*)(in + (size_t)i * 8);
    f32x4 a = p[0], b = p[1];
    short8v o;
#pragma unroll
    for (int k = 0; k < 4; k++) { o[k] = f2bf(a[k]); o[k + 4] = f2bf(b[k]); }
    *(short8v*)(out + (size_t)i * 8) = o;
  }
}

// ---------------- C[m][n] = tanh(sum_k A[m][k]*B[n][k] + bias[n]) ----------------
// m97-style 128x128x32 bf16 MFMA GEMM, both operands K-major.
__global__ __launch_bounds__(256) void gemm_tanh(const short* __restrict__ A,
                                                 const short* __restrict__ Bw,
                                                 const float* __restrict__ bias,
                                                 short* __restrict__ C,
                                                 int M, int N, int K) {
  __shared__ short lA[128 * 32];
  __shared__ short lB[128 * 32];
  const int tid = threadIdx.x;
  const int wid = tid >> 6, lane = tid & 63;
  const int lo = lane & 15, hi = lane >> 4;
  const int nbm = M >> 7;
  const int bm = blockIdx.x % nbm, bn = blockIdx.x / nbm;
  const int wm = wid >> 1, wn = wid & 1;

  f32x4 acc[4][4] = {};

  const short* Ab = A + (size_t)(bm * 128 + (tid >> 2)) * K + (tid & 3) * 8;
  const short* Bb = Bw + (size_t)(bn * 128 + (tid >> 2)) * K + (tid & 3) * 8;
  short* lAd = lA + tid * 8;
  short* lBd = lB + tid * 8;

  for (int kt = 0; kt < K; kt += 32) {
    __syncthreads();
    gl_lds16(Ab + kt, lAd);
    gl_lds16(Ab + (size_t)64 * K + kt, lAd + 64 * 32);
    gl_lds16(Bb + kt, lBd);
    gl_lds16(Bb + (size_t)64 * K + kt, lBd + 64 * 32);
    asm volatile("s_waitcnt vmcnt(0)" ::: "memory");
    __syncthreads();
    short8v aF[4], bF[4];
#pragma unroll
    for (int f = 0; f < 4; f++) {
      aF[f] = *(const short8v*)(lA + (wm * 64 + f * 16 + lo) * 32 + hi * 8);
      bF[f] = *(const short8v*)(lB + (wn * 64 + f * 16 + lo) * 32 + hi * 8);
    }
#pragma unroll
    for (int mf = 0; mf < 4; mf++)
#pragma unroll
      for (int nf = 0; nf < 4; nf++)
        acc[mf][nf] = __builtin_amdgcn_mfma_f32_16x16x32_bf16(aF[mf], bF[nf],
                                                              acc[mf][nf], 0, 0, 0);
  }
  const int cm0 = bm * 128 + wm * 64;
  const int cn0 = bn * 128 + wn * 64;
#pragma unroll
  for (int nf = 0; nf < 4; nf++) {
    int col = cn0 + nf * 16 + lo;
    float bv = bias[col];
#pragma unroll
    for (int mf = 0; mf < 4; mf++) {
      int row = cm0 + mf * 16 + hi * 4;
#pragma unroll
      for (int i = 0; i < 4; i++) {
        C[(size_t)(row + i) * N + col] = f2bf(tanhf(acc[mf][nf][i] + bv));
      }
    }
  }
}

// ---------------- persistent recurrence kernel (one layer) ----------------
// g = sigmoid(h @ Whh^T + bhh); h' = g*h + (1-g)*ta[t]
// 32 WGs x 256 thr; 128 waves; wave = 16 j-cols x 16 batch tile.
// Whh held in VGPRs as A-frags; h broadcast via swizzled bf16 image in global,
// staged to LDS each step; custom monotonic device-scope spin barrier.
//
// Release protocol per step (race-fixed R1): store h-slice -> __syncthreads()
// (drains ALL waves' vmem: compiler emits s_waitcnt vmcnt(0) before s_barrier)
// -> __threadfence() (agent-scope L2 writeback) -> release atomicAdd ->
// acquire spin -> __syncthreads().
__global__ __launch_bounds__(256, 1) void recur(const short* __restrict__ ta,
                                                const short* __restrict__ whh,
                                                const float* __restrict__ bhh,
                                                const float* __restrict__ h0,
                                                short* __restrict__ himg,
                                                short* __restrict__ ybf,
                                                float* __restrict__ yf32,
                                                float* __restrict__ hyout,
                                                u32* __restrict__ barcnt) {
  __shared__ short hl[Bn * Hn];  // 64 KB swizzled h image
  const int tid = threadIdx.x;
  const int wid = tid >> 6, lane = tid & 63;
  const int lo = lane & 15, hi = lane >> 4;
  const int gw = blockIdx.x * 4 + wid;  // 0..127
  const int jt = gw >> 1, bt = gw & 1;
  const int b = bt * 16 + lo;        // batch row (B-frag col / D col)
  const int j0 = jt * 16 + hi * 4;   // this lane's 4 output j's (D rows)
  const int jA = jt * 16 + lo;       // A-frag row (weight j)
  const int koff = hi * 8;

  // weights resident in registers as pre-formatted A-frags: 128 VGPRs
  short8v wA[32];
#pragma unroll
  for (int s = 0; s < 32; s++)
    wA[s] = *(const short8v*)(whh + (size_t)jA * Hn + s * 32 + koff);

  f32x4 bias = *(const f32x4*)(bhh + j0);
  f32x4 hreg = *(const f32x4*)(h0 + (size_t)b * Hn + j0);

  const u32 hxor = (u32)((b & 7) << 4);
  const u32 hstore = ((u32)(b * 2048 + j0 * 2)) ^ hxor;  // swizzled byte offset
  const u32 hbase = (u32)(b * 2048 + koff * 2);

  {  // init h image [0]
    short4v hv;
#pragma unroll
    for (int i = 0; i < 4; i++) hv[i] = f2bf(hreg[i]);
    *(short4v*)((char*)himg + hstore) = hv;
  }
  __syncthreads();   // all waves' stores drained to L2
  __threadfence();   // agent-scope release (L2 writeback)
  if (tid == 0) {
    __hip_atomic_fetch_add(barcnt, 1u, __ATOMIC_RELEASE, __HIP_MEMORY_SCOPE_AGENT);
    while (__hip_atomic_load(barcnt, __ATOMIC_ACQUIRE, __HIP_MEMORY_SCOPE_AGENT) <
           (u32)NWG)
      __builtin_amdgcn_s_sleep(1);
  }
  __syncthreads();

  for (int t = 0; t < Tn; t++) {
    // prefetch this lane's tanh(a_t) values
    short4v tv = *(const short4v*)(ta + (size_t)t * (Bn * Hn) + b * Hn + j0);
    // stage swizzled h image -> LDS (linear copy; swizzle baked into global image)
    const char* src = (const char*)himg + (size_t)(t & 1) * (Bn * Hn * 2);
#pragma unroll
    for (int c = 0; c < 16; c++)
      gl_lds16(src + c * 4096 + tid * 16, (char*)hl + c * 4096 + tid * 16);
    asm volatile("s_waitcnt vmcnt(0)" ::: "memory");
    __syncthreads();

    f32x4 a0 = {0, 0, 0, 0}, a1 = {0, 0, 0, 0}, a2 = {0, 0, 0, 0}, a3 = {0, 0, 0, 0};
#pragma unroll
    for (int s = 0; s < 32; s += 4) {
      short8v v0 = *(const short8v*)((char*)hl + ((hbase + s * 64) ^ hxor));
      short8v v1 = *(const short8v*)((char*)hl + ((hbase + s * 64 + 64) ^ hxor));
      short8v v2 = *(const short8v*)((char*)hl + ((hbase + s * 64 + 128) ^ hxor));
      short8v v3 = *(const short8v*)((char*)hl + ((hbase + s * 64 + 192) ^ hxor));
      a0 = __builtin_amdgcn_mfma_f32_16x16x32_bf16(wA[s], v0, a0, 0, 0, 0);
      a1 = __builtin_amdgcn_mfma_f32_16x16x32_bf16(wA[s + 1], v1, a1, 0, 0, 0);
      a2 = __builtin_amdgcn_mfma_f32_16x16x32_bf16(wA[s + 2], v2, a2, 0, 0, 0);
      a3 = __builtin_amdgcn_mfma_f32_16x16x32_bf16(wA[s + 3], v3, a3, 0, 0, 0);
    }
    f32x4 xv = (a0 + a1) + (a2 + a3) + bias;
    f32x4 hn;
#pragma unroll
    for (int i = 0; i < 4; i++) {
      float g = 1.0f / (1.0f + __expf(-xv[i]));
      hn[i] = g * hreg[i] + (1.0f - g) * bf2f(tv[i]);
    }
    hreg = hn;
    short4v hb;
#pragma unroll
    for (int i = 0; i < 4; i++) hb[i] = f2bf(hn[i]);
    *(short4v*)((char*)himg + (size_t)((t + 1) & 1) * (Bn * Hn * 2) + hstore) = hb;
    if (ybf) *(short4v*)(ybf + (size_t)t * (Bn * Hn) + b * Hn + j0) = hb;
    if (yf32) *(f32x4*)(yf32 + (size_t)t * (Bn * Hn) + b * Hn + j0) = hn;

    if (t != Tn - 1) {
      __syncthreads();   // drains ALL waves' h stores (waitcnt before barrier)
      __threadfence();   // agent-scope release of h image
      if (tid == 0) {
        __hip_atomic_fetch_add(barcnt, 1u, __ATOMIC_RELEASE,
                               __HIP_MEMORY_SCOPE_AGENT);
        u32 tgt = (u32)NWG * (t + 2);
        while (__hip_atomic_load(barcnt, __ATOMIC_ACQUIRE, __HIP_MEMORY_SCOPE_AGENT) <
               tgt)
          __builtin_amdgcn_s_sleep(1);
      }
      __syncthreads();
    }
  }
  *(f32x4*)(hyout + (size_t)b * Hn + j0) = hreg;
}

extern "C" void kernel_launch(void* const* d_in, const int* in_sizes, int n_in,
                              void* d_out, int out_size, void* d_ws, size_t ws_size,
                              hipStream_t stream) {
  const float* x = (const float*)d_in[0];
  const float* hx = (const float*)d_in[1];
  const float* wih0 = (const float*)d_in[2];
  const float* whh0 = (const float*)d_in[3];
  const float* bih0 = (const float*)d_in[4];
  const float* bhh0 = (const float*)d_in[5];
  const float* wih1 = (const float*)d_in[6];
  const float* whh1 = (const float*)d_in[7];
  const float* bih1 = (const float*)d_in[8];
  const float* bhh1 = (const float*)d_in[9];
  float* out = (float*)d_out;  // [T*B*H] y1  then [2*B*H] hy

  char* ws = (char*)d_ws;
  size_t o = 0;
  short* xb = (short*)(ws + o);    o += (size_t)Tn * Bn * Hn * 2;
  short* tbuf = (short*)(ws + o);  o += (size_t)Tn * Bn * Hn * 2;  // ta0 then ta1
  short* y0 = (short*)(ws + o);    o += (size_t)Tn * Bn * Hn * 2;
  short* bwih0 = (short*)(ws + o); o += (size_t)Hn * Hn * 2;
  short* bwhh0 = (short*)(ws + o); o += (size_t)Hn * Hn * 2;
  short* bwih1 = (short*)(ws + o); o += (size_t)Hn * Hn * 2;
  short* bwhh1 = (short*)(ws + o); o += (size_t)Hn * Hn * 2;
  short* himg0 = (short*)(ws + o); o += (size_t)2 * Bn * Hn * 2;
  short* himg1 = (short*)(ws + o); o += (size_t)2 * Bn * Hn * 2;
  u32* bars = (u32*)(ws + o);      o += 256;

  hipMemsetAsync(bars, 0, 256, stream);

  cvt_bf16<<<2048, 256, 0, stream>>>(x, xb, Tn * Bn * Hn / 8);
  cvt_bf16<<<256, 256, 0, stream>>>(wih0, bwih0, Hn * Hn / 8);
  cvt_bf16<<<256, 256, 0, stream>>>(whh0, bwhh0, Hn * Hn / 8);
  cvt_bf16<<<256, 256, 0, stream>>>(whh1, bwhh1, Hn * Hn / 8);
  cvt_bf16<<<256, 256, 0, stream>>>(wih1, bwih1, Hn * Hn / 8);

  gemm_tanh<<<(Tn * Bn / 128) * (Hn / 128), 256, 0, stream>>>(
      xb, bwih0, bih0, tbuf, Tn * Bn, Hn, Hn);
  recur<<<NWG, 256, 0, stream>>>(tbuf, bwhh0, bhh0, hx, himg0, y0, nullptr,
                                 out + (size_t)Tn * Bn * Hn, bars);
  gemm_tanh<<<(Tn * Bn / 128) * (Hn / 128), 256, 0, stream>>>(
      y0, bwih1, bih1, tbuf, Tn * Bn, Hn, Hn);
  recur<<<NWG, 256, 0, stream>>>(tbuf, bwhh1, bhh1, hx + (size_t)Bn * Hn, himg1,
                                 nullptr, (float*)d_out,
                                 out + (size_t)Tn * Bn * Hn + (size_t)Bn * Hn,
                                 bars + 16);
}

// Round 3
// 6604.774 us; speedup vs baseline: 1.9428x; 1.9428x over previous
//
#include <hip/hip_runtime.h>

typedef unsigned int u32;
typedef unsigned long long u64;
typedef short short4v __attribute__((ext_vector_type(4)));
typedef short short8v __attribute__((ext_vector_type(8)));
typedef float f32x4 __attribute__((ext_vector_type(4)));

#define Tn 1024
#define Bn 32
#define Hn 1024
#define NWG 32

__device__ __forceinline__ float bf2f(short s) {
  u32 u = ((u32)(unsigned short)s) << 16;
  return __builtin_bit_cast(float, u);
}
__device__ __forceinline__ short f2bf(float f) {
  u32 u = __builtin_bit_cast(u32, f);
  u32 r = (u + 0x7fffu + ((u >> 16) & 1u)) >> 16;
  return (short)(unsigned short)r;
}

__device__ __forceinline__ void gl_lds16(const void* g, void* l) {
  __builtin_amdgcn_global_load_lds(
      (const __attribute__((address_space(1))) u32*)g,
      (__attribute__((address_space(3))) u32*)l, 16, 0, 0);
}
// sc0|sc1 (0x11): agent-coherent read — sourced from L3 coherence point,
// bypasses (and does not require invalidating) the per-XCD L2.
__device__ __forceinline__ void gl_lds16_coh(const void* g, void* l) {
  __builtin_amdgcn_global_load_lds(
      (const __attribute__((address_space(1))) u32*)g,
      (__attribute__((address_space(3))) u32*)l, 16, 0, 0x11);
}

// ---------------- fp32 -> bf16 conversion (vectorized) ----------------
__global__ __launch_bounds__(256) void cvt_bf16(const float* __restrict__ in,
                                                short* __restrict__ out, int n8) {
  int stride = gridDim.x * 256;
  for (int i = blockIdx.x * 256 + threadIdx.x; i < n8; i += stride) {
    const f32x4* p = (const f32x4*)(in + (size_t)i * 8);
    f32x4 a = p[0], b = p[1];
    short8v o;
#pragma unroll
    for (int k = 0; k < 4; k++) { o[k] = f2bf(a[k]); o[k + 4] = f2bf(b[k]); }
    *(short8v*)(out + (size_t)i * 8) = o;
  }
}

// ---------------- C[m][n] = tanh(sum_k A[m][k]*B[n][k] + bias[n]) ----------------
// m97-style 128x128x32 bf16 MFMA GEMM, both operands K-major.
__global__ __launch_bounds__(256) void gemm_tanh(const short* __restrict__ A,
                                                 const short* __restrict__ Bw,
                                                 const float* __restrict__ bias,
                                                 short* __restrict__ C,
                                                 int M, int N, int K) {
  __shared__ short lA[128 * 32];
  __shared__ short lB[128 * 32];
  const int tid = threadIdx.x;
  const int wid = tid >> 6, lane = tid & 63;
  const int lo = lane & 15, hi = lane >> 4;
  const int nbm = M >> 7;
  const int bm = blockIdx.x % nbm, bn = blockIdx.x / nbm;
  const int wm = wid >> 1, wn = wid & 1;

  f32x4 acc[4][4] = {};

  const short* Ab = A + (size_t)(bm * 128 + (tid >> 2)) * K + (tid & 3) * 8;
  const short* Bb = Bw + (size_t)(bn * 128 + (tid >> 2)) * K + (tid & 3) * 8;
  short* lAd = lA + tid * 8;
  short* lBd = lB + tid * 8;

  for (int kt = 0; kt < K; kt += 32) {
    __syncthreads();
    gl_lds16(Ab + kt, lAd);
    gl_lds16(Ab + (size_t)64 * K + kt, lAd + 64 * 32);
    gl_lds16(Bb + kt, lBd);
    gl_lds16(Bb + (size_t)64 * K + kt, lBd + 64 * 32);
    asm volatile("s_waitcnt vmcnt(0)" ::: "memory");
    __syncthreads();
    short8v aF[4], bF[4];
#pragma unroll
    for (int f = 0; f < 4; f++) {
      aF[f] = *(const short8v*)(lA + (wm * 64 + f * 16 + lo) * 32 + hi * 8);
      bF[f] = *(const short8v*)(lB + (wn * 64 + f * 16 + lo) * 32 + hi * 8);
    }
#pragma unroll
    for (int mf = 0; mf < 4; mf++)
#pragma unroll
      for (int nf = 0; nf < 4; nf++)
        acc[mf][nf] = __builtin_amdgcn_mfma_f32_16x16x32_bf16(aF[mf], bF[nf],
                                                              acc[mf][nf], 0, 0, 0);
  }
  const int cm0 = bm * 128 + wm * 64;
  const int cn0 = bn * 128 + wn * 64;
#pragma unroll
  for (int nf = 0; nf < 4; nf++) {
    int col = cn0 + nf * 16 + lo;
    float bv = bias[col];
#pragma unroll
    for (int mf = 0; mf < 4; mf++) {
      int row = cm0 + mf * 16 + hi * 4;
#pragma unroll
      for (int i = 0; i < 4; i++) {
        C[(size_t)(row + i) * N + col] = f2bf(tanhf(acc[mf][nf][i] + bv));
      }
    }
  }
}

// ---------------- persistent recurrence kernel (one layer) ----------------
// g = sigmoid(h @ Whh^T + bhh); h' = g*h + (1-g)*ta[t]
// 32 WGs x 256 thr; 128 waves; wave = 16 j-cols x 16 batch tile.
// Whh held in registers as A-frags; h broadcast via swizzled bf16 image in
// global memory using agent-coherent (sc0 sc1) stores/loads that transit the
// L3 coherence point directly -- NO L2 writeback/invalidate anywhere:
//   store h (relaxed agent atomic, sc0sc1) -> __syncthreads (drains vmcnt per
//   wave) -> tid0 relaxed atomicAdd -> relaxed spin -> __syncthreads ->
//   gl_lds16 aux=0x11 (reads fresh from L3).
__global__ __launch_bounds__(256, 1) void recur(const short* __restrict__ ta,
                                                const short* __restrict__ whh,
                                                const float* __restrict__ bhh,
                                                const float* __restrict__ h0,
                                                short* __restrict__ himg,
                                                short* __restrict__ ybf,
                                                float* __restrict__ yf32,
                                                float* __restrict__ hyout,
                                                u32* __restrict__ barcnt) {
  __shared__ short hl[Bn * Hn];  // 64 KB swizzled h image
  const int tid = threadIdx.x;
  const int wid = tid >> 6, lane = tid & 63;
  const int lo = lane & 15, hi = lane >> 4;
  const int gw = blockIdx.x * 4 + wid;  // 0..127
  const int jt = gw >> 1, bt = gw & 1;
  const int b = bt * 16 + lo;        // batch row (B-frag col / D col)
  const int j0 = jt * 16 + hi * 4;   // this lane's 4 output j's (D rows)
  const int jA = jt * 16 + lo;       // A-frag row (weight j)
  const int koff = hi * 8;

  // weights resident in registers as pre-formatted A-frags: 128 VGPRs
  short8v wA[32];
#pragma unroll
  for (int s = 0; s < 32; s++)
    wA[s] = *(const short8v*)(whh + (size_t)jA * Hn + s * 32 + koff);

  f32x4 bias = *(const f32x4*)(bhh + j0);
  f32x4 hreg = *(const f32x4*)(h0 + (size_t)b * Hn + j0);

  const u32 hxor = (u32)((b & 7) << 4);
  const u32 hstore = ((u32)(b * 2048 + j0 * 2)) ^ hxor;  // swizzled byte offset
  const u32 hbase = (u32)(b * 2048 + koff * 2);

  {  // init h image [0] -- agent-coherent store straight to L3
    short4v hv;
#pragma unroll
    for (int i = 0; i < 4; i++) hv[i] = f2bf(hreg[i]);
    __hip_atomic_store((u64*)((char*)himg + hstore),
                       __builtin_bit_cast(u64, hv), __ATOMIC_RELAXED,
                       __HIP_MEMORY_SCOPE_AGENT);
  }
  __syncthreads();  // all waves' coherent stores vmcnt-drained (at L3)
  if (tid == 0) {
    __hip_atomic_fetch_add(barcnt, 1u, __ATOMIC_RELAXED, __HIP_MEMORY_SCOPE_AGENT);
    while (__hip_atomic_load(barcnt, __ATOMIC_RELAXED, __HIP_MEMORY_SCOPE_AGENT) <
           (u32)NWG)
      __builtin_amdgcn_s_sleep(1);
  }
  __syncthreads();

  for (int t = 0; t < Tn; t++) {
    // prefetch this lane's tanh(a_t) values (normal cached load)
    short4v tv = *(const short4v*)(ta + (size_t)t * (Bn * Hn) + b * Hn + j0);
    // stage swizzled h image -> LDS, agent-coherent (sourced from L3)
    const char* src = (const char*)himg + (size_t)(t & 1) * (Bn * Hn * 2);
#pragma unroll
    for (int c = 0; c < 16; c++)
      gl_lds16_coh(src + c * 4096 + tid * 16, (char*)hl + c * 4096 + tid * 16);
    asm volatile("s_waitcnt vmcnt(0)" ::: "memory");
    __syncthreads();

    f32x4 a0 = {0, 0, 0, 0}, a1 = {0, 0, 0, 0}, a2 = {0, 0, 0, 0}, a3 = {0, 0, 0, 0};
#pragma unroll
    for (int s = 0; s < 32; s += 4) {
      short8v v0 = *(const short8v*)((char*)hl + ((hbase + s * 64) ^ hxor));
      short8v v1 = *(const short8v*)((char*)hl + ((hbase + s * 64 + 64) ^ hxor));
      short8v v2 = *(const short8v*)((char*)hl + ((hbase + s * 64 + 128) ^ hxor));
      short8v v3 = *(const short8v*)((char*)hl + ((hbase + s * 64 + 192) ^ hxor));
      a0 = __builtin_amdgcn_mfma_f32_16x16x32_bf16(wA[s], v0, a0, 0, 0, 0);
      a1 = __builtin_amdgcn_mfma_f32_16x16x32_bf16(wA[s + 1], v1, a1, 0, 0, 0);
      a2 = __builtin_amdgcn_mfma_f32_16x16x32_bf16(wA[s + 2], v2, a2, 0, 0, 0);
      a3 = __builtin_amdgcn_mfma_f32_16x16x32_bf16(wA[s + 3], v3, a3, 0, 0, 0);
    }
    f32x4 xv = (a0 + a1) + (a2 + a3) + bias;
    f32x4 hn;
#pragma unroll
    for (int i = 0; i < 4; i++) {
      float g = 1.0f / (1.0f + __expf(-xv[i]));
      hn[i] = g * hreg[i] + (1.0f - g) * bf2f(tv[i]);
    }
    hreg = hn;
    short4v hb;
#pragma unroll
    for (int i = 0; i < 4; i++) hb[i] = f2bf(hn[i]);
    __hip_atomic_store(
        (u64*)((char*)himg + (size_t)((t + 1) & 1) * (Bn * Hn * 2) + hstore),
        __builtin_bit_cast(u64, hb), __ATOMIC_RELAXED, __HIP_MEMORY_SCOPE_AGENT);
    if (ybf) *(short4v*)(ybf + (size_t)t * (Bn * Hn) + b * Hn + j0) = hb;
    if (yf32) *(f32x4*)(yf32 + (size_t)t * (Bn * Hn) + b * Hn + j0) = hn;

    if (t != Tn - 1) {
      __syncthreads();  // drains ALL waves' coherent h stores (vmcnt before barrier)
      if (tid == 0) {
        __hip_atomic_fetch_add(barcnt, 1u, __ATOMIC_RELAXED,
                               __HIP_MEMORY_SCOPE_AGENT);
        u32 tgt = (u32)NWG * (t + 2);
        while (__hip_atomic_load(barcnt, __ATOMIC_RELAXED,
                                 __HIP_MEMORY_SCOPE_AGENT) < tgt)
          __builtin_amdgcn_s_sleep(1);
      }
      __syncthreads();
    }
  }
  *(f32x4*)(hyout + (size_t)b * Hn + j0) = hreg;
}

extern "C" void kernel_launch(void* const* d_in, const int* in_sizes, int n_in,
                              void* d_out, int out_size, void* d_ws, size_t ws_size,
                              hipStream_t stream) {
  const float* x = (const float*)d_in[0];
  const float* hx = (const float*)d_in[1];
  const float* wih0 = (const float*)d_in[2];
  const float* whh0 = (const float*)d_in[3];
  const float* bih0 = (const float*)d_in[4];
  const float* bhh0 = (const float*)d_in[5];
  const float* wih1 = (const float*)d_in[6];
  const float* whh1 = (const float*)d_in[7];
  const float* bih1 = (const float*)d_in[8];
  const float* bhh1 = (const float*)d_in[9];
  float* out = (float*)d_out;  // [T*B*H] y1  then [2*B*H] hy

  char* ws = (char*)d_ws;
  size_t o = 0;
  short* xb = (short*)(ws + o);    o += (size_t)Tn * Bn * Hn * 2;
  short* tbuf = (short*)(ws + o);  o += (size_t)Tn * Bn * Hn * 2;  // ta0 then ta1
  short* y0 = (short*)(ws + o);    o += (size_t)Tn * Bn * Hn * 2;
  short* bwih0 = (short*)(ws + o); o += (size_t)Hn * Hn * 2;
  short* bwhh0 = (short*)(ws + o); o += (size_t)Hn * Hn * 2;
  short* bwih1 = (short*)(ws + o); o += (size_t)Hn * Hn * 2;
  short* bwhh1 = (short*)(ws + o); o += (size_t)Hn * Hn * 2;
  short* himg0 = (short*)(ws + o); o += (size_t)2 * Bn * Hn * 2;
  short* himg1 = (short*)(ws + o); o += (size_t)2 * Bn * Hn * 2;
  u32* bars = (u32*)(ws + o);      o += 256;

  hipMemsetAsync(bars, 0, 256, stream);

  cvt_bf16<<<2048, 256, 0, stream>>>(x, xb, Tn * Bn * Hn / 8);
  cvt_bf16<<<256, 256, 0, stream>>>(wih0, bwih0, Hn * Hn / 8);
  cvt_bf16<<<256, 256, 0, stream>>>(whh0, bwhh0, Hn * Hn / 8);
  cvt_bf16<<<256, 256, 0, stream>>>(whh1, bwhh1, Hn * Hn / 8);
  cvt_bf16<<<256, 256, 0, stream>>>(wih1, bwih1, Hn * Hn / 8);

  gemm_tanh<<<(Tn * Bn / 128) * (Hn / 128), 256, 0, stream>>>(
      xb, bwih0, bih0, tbuf, Tn * Bn, Hn, Hn);
  recur<<<NWG, 256, 0, stream>>>(tbuf, bwhh0, bhh0, hx, himg0, y0, nullptr,
                                 out + (size_t)Tn * Bn * Hn, bars);
  gemm_tanh<<<(Tn * Bn / 128) * (Hn / 128), 256, 0, stream>>>(
      y0, bwih1, bih1, tbuf, Tn * Bn, Hn, Hn);
  recur<<<NWG, 256, 0, stream>>>(tbuf, bwhh1, bhh1, hx + (size_t)Bn * Hn, himg1,
                                 nullptr, (float*)d_out,
                                 out + (size_t)Tn * Bn * Hn + (size_t)Bn * Hn,
                                 bars + 16);
}